// Round 13
// baseline (540.944 us; speedup 1.0000x reference)
//
#include <hip/hip_runtime.h>
#include <hip/hip_bf16.h>
#include <math.h>

// GAT x3 on N=100000 nodes, E=1600000 edges (+ self loops).
// Round 18: src-sorted CSR segments for gather locality. z6/agg4 gathers
// were compulsory-traffic bound (hpA reuse factor ~1: random src order means
// every XCD refetches every line). Sorting each dst segment by src (64-lane
// bitonic shfl sort, one wave/node; segments >64 left unsorted - pure opt)
// makes concurrently-resident waves walk src-space in a synchronized band
// (~1.5-3MB) that fits per-XCD L2 -> each line fetched ~once, reused ~16x.
// Edge order within a segment is semantically free (was nondeterministic).
// (R17: z6 4-edge MLP; R16: scores in featB line, 2 lines/edge; R15: bf16
// gather tables; R14: split aligned tables; R10: fused weights in LDS;
// R9: feature12 LDS-B; R8: bucketed CSR build.)

#define NN 100000
#define NE 1600000
#define NT (NE + NN)
#define FIN 50
#define HID 40
#define COUT 121

#define NB 128           // buckets
#define NPB 782          // nodes per bucket (128*782 = 100096 >= NN)
#define EPB 8192         // edges per bin block

typedef __attribute__((ext_vector_type(8))) short bf16x8;
typedef __attribute__((ext_vector_type(4))) float f32x4;

__device__ __forceinline__ float lrelu(float x) { return fmaxf(x, 0.2f * x); }
__device__ __forceinline__ float elu1(float x)  { return x > 0.f ? x : __expf(x) - 1.f; }
__device__ __forceinline__ unsigned pkbf(float a, float b) {
    __hip_bfloat16 ha = __float2bfloat16(a), hb = __float2bfloat16(b);
    return ((unsigned)*reinterpret_cast<unsigned short*>(&hb) << 16) |
           *reinterpret_cast<unsigned short*>(&ha);
}
__device__ __forceinline__ float bflo(unsigned u) { return __uint_as_float(u << 16); }
__device__ __forceinline__ float bfhi(unsigned u) { return __uint_as_float(u & 0xffff0000u); }

// ---------------- bucketed CSR build ----------------
__global__ __launch_bounds__(256)
void zero_bcnt_kernel(int* __restrict__ bcnt) {
    int t = threadIdx.x;
    if (t < NB) bcnt[t] = 0;
}

__global__ __launch_bounds__(256)
void bin_count_kernel(const int* __restrict__ edst, int* __restrict__ bcnt) {
    __shared__ int h[NB];
    int t = threadIdx.x;
    if (t < NB) h[t] = 0;
    __syncthreads();
    int e0 = blockIdx.x * EPB;
    for (int q = 0; q < EPB; q += 256) {
        int e = e0 + q + t;
        if (e < NE) atomicAdd(&h[edst[e] / NPB], 1);
    }
    __syncthreads();
    if (t < NB && h[t]) atomicAdd(&bcnt[t], h[t]);
}

__global__ __launch_bounds__(256)
void bin_scan_kernel(const int* __restrict__ bcnt, int* __restrict__ boff,
                     int* __restrict__ bcur) {
    __shared__ int s[NB];
    int t = threadIdx.x;
    if (t < NB) s[t] = bcnt[t];
    __syncthreads();
    if (t == 0) {
        int run = 0;
        for (int i = 0; i < NB; i++) { int c = s[i]; s[i] = run; run += c; }
        boff[NB] = run;   // == NE
    }
    __syncthreads();
    if (t < NB) { boff[t] = s[t]; bcur[t] = s[t]; }
}

// Each block claims a contiguous chunk per bucket, then writes packed records
// src | (dst_in_bucket << 17) into its exclusive chunk (dense, short window).
__global__ __launch_bounds__(256)
void bin_place_kernel(const int* __restrict__ esrc, const int* __restrict__ edst,
                      int* __restrict__ bcur, int* __restrict__ ebuf) {
    __shared__ int h[NB], base[NB], lcur[NB];
    int t = threadIdx.x;
    if (t < NB) h[t] = 0;
    __syncthreads();
    int e0 = blockIdx.x * EPB;
    for (int q = 0; q < EPB; q += 256) {
        int e = e0 + q + t;
        if (e < NE) atomicAdd(&h[edst[e] / NPB], 1);
    }
    __syncthreads();
    if (t < NB) {
        int c = h[t];
        base[t] = c ? atomicAdd(&bcur[t], c) : 0;
        lcur[t] = 0;
    }
    __syncthreads();
    for (int q = 0; q < EPB; q += 256) {
        int e = e0 + q + t;
        if (e < NE) {
            int d = edst[e], s = esrc[e];
            int b = d / NPB;
            int r = atomicAdd(&lcur[b], 1);
            ebuf[base[b] + r] = s | ((d - b * NPB) << 17);
        }
    }
}

// One block per bucket: per-node degree via LDS histogram.
__global__ __launch_bounds__(256)
void bucket_deg_kernel(const int* __restrict__ boff, const int* __restrict__ ebuf,
                       int* __restrict__ deg) {
    __shared__ int h[NPB];
    int b = blockIdx.x, t = threadIdx.x;
    for (int i = t; i < NPB; i += 256) h[i] = 0;
    __syncthreads();
    int jb = boff[b], je = boff[b + 1];
    for (int j = jb + t; j < je; j += 256) atomicAdd(&h[ebuf[j] >> 17], 1);
    __syncthreads();
    int n0 = b * NPB;
    for (int i = t; i < NPB; i += 256) {
        int n = n0 + i;
        if (n < NN) deg[n] = h[i] + 1;   // +1 self loop
    }
}

// One block per bucket: replay records with LDS cursors; sorted_src writes
// land in this block's exclusive CSR range (L2-local, written back once).
__global__ __launch_bounds__(256)
void bucket_scatter_kernel(const int* __restrict__ boff, const int* __restrict__ ebuf,
                           const int* __restrict__ off, int* __restrict__ sorted_src) {
    __shared__ int lcur[NPB];
    int b = blockIdx.x, t = threadIdx.x;
    int n0 = b * NPB;
    for (int i = t; i < NPB; i += 256) {
        int n = n0 + i;
        lcur[i] = (n < NN) ? off[n] + 1 : 0;   // +1: self loop occupies slot 0
    }
    __syncthreads();
    int jb = boff[b], je = boff[b + 1];
    for (int j = jb + t; j < je; j += 256) {
        int rec = ebuf[j];
        int p = atomicAdd(&lcur[rec >> 17], 1);
        sorted_src[p] = rec & 0x1FFFF;
    }
}

// One wave per dst node: sort the segment by src id (64-lane bitonic via
// shfl_xor). Pure locality optimization - segments >64 edges left unsorted.
__global__ __launch_bounds__(256)
void seg_sort_kernel(const int* __restrict__ off, int* __restrict__ srt) {
    int wid = (blockIdx.x * 256 + threadIdx.x) >> 6;
    int d = __builtin_amdgcn_readfirstlane(wid);
    if (d >= NN) return;
    int lane = threadIdx.x & 63;
    int jb = off[d], je = off[d + 1];
    int n = je - jb;
    if (n > 64 || n < 2) return;
    int v = (lane < n) ? srt[jb + lane] : 0x7FFFFFFF;
#pragma unroll
    for (int k = 2; k <= 64; k <<= 1) {
#pragma unroll
        for (int j = k >> 1; j > 0; j >>= 1) {
            int p = __shfl_xor(v, j, 64);
            bool up = ((lane & k) == 0);
            bool keepMin = (((lane & j) == 0) == up);
            int mn = min(v, p), mx = max(v, p);
            v = keepMin ? mn : mx;
        }
    }
    if (lane < n) srt[jb + lane] = v;
}

// ---------------- node-offset scan ----------------
__global__ __launch_bounds__(256)
void scan_block_kernel(const int* __restrict__ deg, int* __restrict__ off,
                       int* __restrict__ bsum) {
    __shared__ int s[256];
    int t = threadIdx.x, b = blockIdx.x, i = b * 256 + t;
    int v = (i < NN) ? deg[i] : 0;
    s[t] = v; __syncthreads();
#pragma unroll
    for (int o = 1; o < 256; o <<= 1) {
        int x = (t >= o) ? s[t - o] : 0;
        __syncthreads();
        s[t] += x;
        __syncthreads();
    }
    if (i < NN) off[i] = s[t] - v;
    if (t == 255) bsum[b] = s[255];
}

__global__ __launch_bounds__(256)
void scan_bsum_kernel(const int* __restrict__ bsum, int* __restrict__ bscan, int nb) {
    __shared__ int s[256];
    int t = threadIdx.x;
    int carry = 0;
    int nc = (nb + 255) / 256;
    for (int c = 0; c < nc; c++) {
        int i = c * 256 + t;
        int v = (i < nb) ? bsum[i] : 0;
        s[t] = v; __syncthreads();
#pragma unroll
        for (int o = 1; o < 256; o <<= 1) {
            int x = (t >= o) ? s[t - o] : 0;
            __syncthreads();
            s[t] += x;
            __syncthreads();
        }
        if (i < nb) bscan[i] = carry + s[t] - v;
        carry += s[255];
        __syncthreads();
    }
}

__global__ __launch_bounds__(256)
void place_kernel(int* __restrict__ off, const int* __restrict__ bscan,
                  int* __restrict__ sorted_src) {
    int i = blockIdx.x * 256 + threadIdx.x;
    if (i == 0) off[NN] = NT;
    if (i < NN) {
        int o = off[i] + bscan[i >> 8];
        off[i] = o;
        sorted_src[o] = i;   // self loop first
    }
}

// ---------------- fold weight blocks ----------------
__global__ __launch_bounds__(256)
void fold_B12_kernel(const float* __restrict__ W, const float* __restrict__ lw,
                     const float* __restrict__ as_, const float* __restrict__ ad_,
                     float* __restrict__ B, int F) {
    int t = blockIdx.x * 256 + threadIdx.x;
    if (t >= F * 88) return;
    int f = t / 88, j = t - f * 88;
    float v = 0.f;
    if (j < 40) v = W[f * 40 + j];
    else if (j < 80) v = lw[f * 40 + (j - 40)];
    else if (j < 84) {
        int h = j - 80; float s = 0.f;
        for (int d = 0; d < 10; d++) s += W[f * 40 + h * 10 + d] * as_[h * 10 + d];
        v = s;
    } else {
        int h = j - 84; float s = 0.f;
        for (int d = 0; d < 10; d++) s += W[f * 40 + h * 10 + d] * ad_[h * 10 + d];
        v = s;
    }
    B[t] = v;
}

__global__ __launch_bounds__(256)
void fold_B3_kernel(const float* __restrict__ W3, const float* __restrict__ as3,
                    const float* __restrict__ ad3, float* __restrict__ B) {
    int t = blockIdx.x * 256 + threadIdx.x;
    if (t >= 40 * 12) return;
    int f = t / 12, k = t - f * 12;
    float s = 0.f;
    if (k < 6) {
        int h = k;
        for (int c = 0; c < COUT; c++) s += W3[f * 726 + h * COUT + c] * as3[h * COUT + c];
    } else {
        int h = k - 6;
        for (int c = 0; c < COUT; c++) s += W3[f * 726 + h * COUT + c] * ad3[h * COUT + c];
    }
    B[t] = s;
}

// Fold W3/lw3 into bf16 MFMA B-fragment order.
__global__ __launch_bounds__(256)
void fold_Bf_kernel(const float* __restrict__ W3, const float* __restrict__ lw3,
                    __hip_bfloat16* __restrict__ Bf) {
    int t = blockIdx.x * 256 + threadIdx.x;
    if (t >= 9 * 8 * 64 * 8) return;
    int j = t & 7, lane = (t >> 3) & 63, ct = (t >> 9) & 7, kt = t >> 12;
    int k = kt * 32 + (lane >> 4) * 8 + j;
    int c = ct * 16 + (lane & 15);
    float v = 0.f;
    if (c < COUT) {
        if (k < 240) {
            int h = k / 40, f = k - h * 40;
            v = W3[f * 726 + h * COUT + c];
        } else if (k < 280) {
            int f = k - 240;
            v = lw3[f * COUT + c];
        }
    }
    Bf[t] = __float2bfloat16(v);
}

// ---------------- fused feature GEMM for layers 1/2 ----------------
// Gather tables: f<32 -> xbA (64B aligned bf16 rows); f in [32,40) + asrc
// scores -> combined xcB[node][16] bf16 (32B rows): [0:8]=feats, [8:12]=
// scores bf16. adst/agg stay fp32.
template <int F>
__global__ __launch_bounds__(256)
void feature12_kernel(const float* __restrict__ A, const float* __restrict__ B,
                      const float* __restrict__ bias, const float* __restrict__ lbias,
                      __hip_bfloat16* __restrict__ xbA, __hip_bfloat16* __restrict__ xcB,
                      float* __restrict__ agg, float* __restrict__ adst) {
    __shared__ float sB[F * 88];
    const int t = threadIdx.x;
    for (int i = t; i < F * 88; i += 256) sB[i] = B[i];

    const int lane = t & 63;
    const int p = __builtin_amdgcn_readfirstlane(t >> 6);
    const int r = blockIdx.x * 64 + lane;
    const bool valid = r < NN;
    const int rr = valid ? r : NN - 1;

    float a[F];
    if (F % 4 == 0) {
        const float4* A4 = reinterpret_cast<const float4*>(A + (size_t)rr * F);
#pragma unroll
        for (int q = 0; q < F / 4; q++) {
            float4 v = A4[q];
            a[4 * q] = v.x; a[4 * q + 1] = v.y; a[4 * q + 2] = v.z; a[4 * q + 3] = v.w;
        }
    } else {
        const float2* A2 = reinterpret_cast<const float2*>(A + (size_t)rr * F);
#pragma unroll
        for (int q = 0; q < F / 2; q++) {
            float2 v = A2[q];
            a[2 * q] = v.x; a[2 * q + 1] = v.y;
        }
        if (F & 1) a[F - 1] = A[(size_t)rr * F + F - 1];
    }
    __syncthreads();

    for (int g = p; g < 11; g += 4) {
        const int j0 = g * 8;
        float acc[8];
#pragma unroll
        for (int k = 0; k < 8; k++) acc[k] = 0.f;
#pragma unroll
        for (int f = 0; f < F; f++) {
            float av = a[f];
            float4 b0 = *reinterpret_cast<const float4*>(&sB[f * 88 + j0]);
            float4 b1 = *reinterpret_cast<const float4*>(&sB[f * 88 + j0 + 4]);
            acc[0] += av * b0.x; acc[1] += av * b0.y;
            acc[2] += av * b0.z; acc[3] += av * b0.w;
            acc[4] += av * b1.x; acc[5] += av * b1.y;
            acc[6] += av * b1.z; acc[7] += av * b1.w;
        }
        if (!valid) continue;
        if (j0 < 32) {
            uint4 v;
            v.x = pkbf(acc[0], acc[1]); v.y = pkbf(acc[2], acc[3]);
            v.z = pkbf(acc[4], acc[5]); v.w = pkbf(acc[6], acc[7]);
            *reinterpret_cast<uint4*>(&xbA[(size_t)r * 32 + j0]) = v;
        } else if (j0 < 40) {   // j0 == 32: tail features -> xcB[0:8]
            uint4 v;
            v.x = pkbf(acc[0], acc[1]); v.y = pkbf(acc[2], acc[3]);
            v.z = pkbf(acc[4], acc[5]); v.w = pkbf(acc[6], acc[7]);
            *reinterpret_cast<uint4*>(&xcB[(size_t)r * 16]) = v;
        } else if (j0 < 80) {
            int j = j0 - 40;
#pragma unroll
            for (int k = 0; k < 8; k++) acc[k] += bias[j + k] + lbias[j + k];
            *reinterpret_cast<float4*>(agg + (size_t)r * 40 + j) =
                make_float4(acc[0], acc[1], acc[2], acc[3]);
            *reinterpret_cast<float4*>(agg + (size_t)r * 40 + j + 4) =
                make_float4(acc[4], acc[5], acc[6], acc[7]);
        } else {                // j0 == 80: scores -> xcB[8:12] bf16; adst fp32
            uint2 sv;
            sv.x = pkbf(acc[0], acc[1]); sv.y = pkbf(acc[2], acc[3]);
            *reinterpret_cast<uint2*>(&xcB[(size_t)r * 16 + 8]) = sv;
            *reinterpret_cast<float4*>(adst + (size_t)r * 8) =
                make_float4(acc[4], acc[5], acc[6], acc[7]);
        }
    }
}

// ---------------- layer 3 scores + bf16 h2 copies (zb + hpA + combined hcB) -
__global__ __launch_bounds__(256)
void feature3_kernel(const float* __restrict__ A, const float* __restrict__ B,
                     float* __restrict__ adst, __hip_bfloat16* __restrict__ zb,
                     __hip_bfloat16* __restrict__ hpA, __hip_bfloat16* __restrict__ hcB) {
    int r = blockIdx.x * 256 + threadIdx.x;
    if (r >= NN) return;
    float a[40];
    const float4* A4 = reinterpret_cast<const float4*>(A + (size_t)r * 40);
#pragma unroll
    for (int q = 0; q < 10; q++) {
        float4 v = A4[q];
        a[4 * q] = v.x; a[4 * q + 1] = v.y; a[4 * q + 2] = v.z; a[4 * q + 3] = v.w;
    }
    __hip_bfloat16* zr = zb + (size_t)r * 288 + 240;
    __hip_bfloat16* ha = hpA + (size_t)r * 32;
    __hip_bfloat16* hb = hcB + (size_t)r * 16;
#pragma unroll
    for (int f = 0; f < 40; f++) {
        __hip_bfloat16 v = __float2bfloat16(a[f]);
        zr[f] = v;
        if (f < 32) ha[f] = v; else hb[f - 32] = v;
    }
#pragma unroll
    for (int f = 40; f < 48; f++) zr[f] = __float2bfloat16(0.f);

    float acc[12];
#pragma unroll
    for (int k = 0; k < 12; k++) acc[k] = 0.f;
#pragma unroll
    for (int f = 0; f < 40; f++) {
        float av = a[f];
#pragma unroll
        for (int k = 0; k < 12; k++) acc[k] += av * B[f * 12 + k];
    }
    uint4 sv;
    sv.x = pkbf(acc[0], acc[1]); sv.y = pkbf(acc[2], acc[3]);
    sv.z = pkbf(acc[4], acc[5]); sv.w = 0u;
    *reinterpret_cast<uint4*>(&hcB[(size_t)r * 16 + 8]) = sv;   // scores [8:14]
    *reinterpret_cast<float4*>(adst + (size_t)r * 8) = make_float4(acc[6], acc[7], acc[8], acc[9]);
    *reinterpret_cast<float2*>(adst + (size_t)r * 8 + 4) = make_float2(acc[10], acc[11]);
}

// ---------------- CSR aggregation, H=4, fused weights (LDS), fused ELU ------
// Round-10 structure, 2 lines/edge: xbA (64B row) + xcB (32B row: tail feats
// AND scores in the same line). 4 gathers/round. src-sorted segments.
__global__ __launch_bounds__(256)
void agg4_csr_kernel(const int* __restrict__ off, const int* __restrict__ srt,
                     const float* __restrict__ adst,
                     const __hip_bfloat16* __restrict__ xbA,
                     const __hip_bfloat16* __restrict__ xcB, float* agg) {
    __shared__ float sW[4][64 * 4];
    __shared__ int   sS[4][64];
    int t = threadIdx.x;
    int wslot = t >> 6;
    int wid = (blockIdx.x * 256 + t) >> 6;
    int d = __builtin_amdgcn_readfirstlane(wid);
    if (d >= NN) return;
    int lane = t & 63;
    bool act = lane < 40;
    int f = act ? lane : 0;
    int hh = f / 10;
    const __hip_bfloat16* xt = (f < 32) ? xbA : xcB;
    const int sh = (f < 32) ? 5 : 4;
    const int fo = (f < 32) ? f : (f - 32);
    float4 bv = *reinterpret_cast<const float4*>(adst + (size_t)d * 8);
    int jb = off[d], je = off[d + 1];
    float acc = 0.f, ds = 0.f;
    for (int c0 = jb; c0 < je; c0 += 64) {
        int cnt = je - c0; if (cnt > 64) cnt = 64;
        if (lane < cnt) {   // phase A: one lane per edge; bf16 scores
            int s = srt[c0 + lane];
            sS[wslot][lane] = s;
            uint2 sv = *reinterpret_cast<const uint2*>(&xcB[(size_t)s * 16 + 8]);
            float4 w;
            w.x = __expf(lrelu(bflo(sv.x) + bv.x));
            w.y = __expf(lrelu(bfhi(sv.x) + bv.y));
            w.z = __expf(lrelu(bflo(sv.y) + bv.z));
            w.w = __expf(lrelu(bfhi(sv.y) + bv.w));
            *reinterpret_cast<float4*>(&sW[wslot][lane * 4]) = w;
        }
        int j = 0;          // phase B: FMA loop (round-10 order)
        for (; j + 3 < cnt; j += 4) {
            int s0 = sS[wslot][j], s1 = sS[wslot][j + 1];
            int s2 = sS[wslot][j + 2], s3 = sS[wslot][j + 3];
            float w0 = sW[wslot][(j + 0) * 4 + hh];
            float w1 = sW[wslot][(j + 1) * 4 + hh];
            float w2 = sW[wslot][(j + 2) * 4 + hh];
            float w3 = sW[wslot][(j + 3) * 4 + hh];
            float x0 = __bfloat162float(xt[((size_t)s0 << sh) + fo]);
            float x1 = __bfloat162float(xt[((size_t)s1 << sh) + fo]);
            float x2 = __bfloat162float(xt[((size_t)s2 << sh) + fo]);
            float x3 = __bfloat162float(xt[((size_t)s3 << sh) + fo]);
            acc += w0 * x0; acc += w1 * x1; acc += w2 * x2; acc += w3 * x3;
            ds += (w0 + w1) + (w2 + w3);
        }
        for (; j < cnt; ++j) {
            int s = sS[wslot][j];
            float w = sW[wslot][j * 4 + hh];
            acc += w * __bfloat162float(xt[((size_t)s << sh) + fo]);
            ds += w;
        }
    }
    if (act) {
        float v = agg[(size_t)d * 40 + f] + acc / ds;
        agg[(size_t)d * 40 + f] = elu1(v);   // ELU fused (layers 1/2 only)
    }
}

// ---------------- CSR aggregation, H=6 -> bf16 z, fused weights (LDS) -------
// Round-10 structure, 2 lines/edge, 4-edge MLP rounds, src-sorted segments.
__global__ __launch_bounds__(256)
void z6_csr_kernel(const int* __restrict__ off, const int* __restrict__ srt,
                   const float* __restrict__ adst,
                   const __hip_bfloat16* __restrict__ hpA,
                   const __hip_bfloat16* __restrict__ hcB, __hip_bfloat16* zb) {
    __shared__ float sW[4][64 * 6];
    __shared__ int   sS[4][64];
    int t = threadIdx.x;
    int wslot = t >> 6;
    int wid = (blockIdx.x * 256 + t) >> 6;
    int d = __builtin_amdgcn_readfirstlane(wid);
    if (d >= NN) return;
    int lane = t & 63;
    bool act = lane < 40;
    int f = act ? lane : 0;
    const __hip_bfloat16* ht = (f < 32) ? hpA : hcB;
    const int sh = (f < 32) ? 5 : 4;
    const int fo = (f < 32) ? f : (f - 32);
    float4 bv0 = *reinterpret_cast<const float4*>(adst + (size_t)d * 8);
    float2 bv1 = *reinterpret_cast<const float2*>(adst + (size_t)d * 8 + 4);
    int jb = off[d], je = off[d + 1];
    float acc[6], ds[6];
#pragma unroll
    for (int h = 0; h < 6; h++) { acc[h] = 0.f; ds[h] = 0.f; }
    for (int c0 = jb; c0 < je; c0 += 64) {
        int cnt = je - c0; if (cnt > 64) cnt = 64;
        if (lane < cnt) {   // phase A: bf16 scores from the combined row
            int s = srt[c0 + lane];
            sS[wslot][lane] = s;
            uint4 sv = *reinterpret_cast<const uint4*>(&hcB[(size_t)s * 16 + 8]);
            float* wp = &sW[wslot][lane * 6];
            *reinterpret_cast<float4*>(wp) = make_float4(
                __expf(lrelu(bflo(sv.x) + bv0.x)), __expf(lrelu(bfhi(sv.x) + bv0.y)),
                __expf(lrelu(bflo(sv.y) + bv0.z)), __expf(lrelu(bfhi(sv.y) + bv0.w)));
            *reinterpret_cast<float2*>(wp + 4) = make_float2(
                __expf(lrelu(bflo(sv.z) + bv1.x)), __expf(lrelu(bfhi(sv.z) + bv1.y)));
        }
        int j = 0;          // phase B: 4-edge rounds (4 gathers in flight)
        for (; j + 3 < cnt; j += 4) {
            int s0 = sS[wslot][j],     s1 = sS[wslot][j + 1];
            int s2 = sS[wslot][j + 2], s3 = sS[wslot][j + 3];
            float hv0 = __bfloat162float(ht[((size_t)s0 << sh) + fo]);
            float hv1 = __bfloat162float(ht[((size_t)s1 << sh) + fo]);
            float hv2 = __bfloat162float(ht[((size_t)s2 << sh) + fo]);
            float hv3 = __bfloat162float(ht[((size_t)s3 << sh) + fo]);
            const float* wp = &sW[wslot][j * 6];
#pragma unroll
            for (int h = 0; h < 6; h++) {
                float w0 = wp[h], w1 = wp[6 + h], w2 = wp[12 + h], w3 = wp[18 + h];
                acc[h] += w0 * hv0; acc[h] += w1 * hv1;
                acc[h] += w2 * hv2; acc[h] += w3 * hv3;
                ds[h] += (w0 + w1) + (w2 + w3);
            }
        }
        for (; j + 1 < cnt; j += 2) {
            int s0 = sS[wslot][j], s1 = sS[wslot][j + 1];
            float hv0 = __bfloat162float(ht[((size_t)s0 << sh) + fo]);
            float hv1 = __bfloat162float(ht[((size_t)s1 << sh) + fo]);
            const float* wp = &sW[wslot][j * 6];
#pragma unroll
            for (int h = 0; h < 6; h++) {
                float w0 = wp[h], w1 = wp[6 + h];
                acc[h] += w0 * hv0; acc[h] += w1 * hv1;
                ds[h] += w0 + w1;
            }
        }
        for (; j < cnt; ++j) {
            int s = sS[wslot][j];
            float hv = __bfloat162float(ht[((size_t)s << sh) + fo]);
            const float* wp = &sW[wslot][j * 6];
#pragma unroll
            for (int h = 0; h < 6; h++) {
                acc[h] += wp[h] * hv;
                ds[h] += wp[h];
            }
        }
    }
    if (act) {
#pragma unroll
        for (int h = 0; h < 6; h++)
            zb[(size_t)d * 288 + h * 40 + f] =
                __float2bfloat16(acc[h] / ds[h] * (1.0f / 6.0f));
    }
}

// ---------------- MFMA GEMM: out[100000x121] = A[100000x288]@B[288x128] + bias
__global__ __launch_bounds__(256)
void zgemm_mfma_kernel(const __hip_bfloat16* __restrict__ Ab,
                       const __hip_bfloat16* __restrict__ Bf,
                       const float* __restrict__ b3, const float* __restrict__ lb3,
                       float* __restrict__ out) {
    const int t = threadIdx.x;
    const int lane = t & 63, w = t >> 6;
    const int wr = w & 1, wc = w >> 1;
    const int n0 = blockIdx.x * 128;
    const short* As = (const short*)Ab;
    const short* Bs = (const short*)Bf;

    f32x4 acc[4][4];
#pragma unroll
    for (int i = 0; i < 4; i++)
#pragma unroll
        for (int j = 0; j < 4; j++) acc[i][j] = (f32x4){0.f, 0.f, 0.f, 0.f};

    const int arow = n0 + wr * 64 + (lane & 15);
    const int koff = (lane >> 4) * 8;

    for (int kk = 0; kk < 9; kk++) {
        bf16x8 af[4], bfr[4];
#pragma unroll
        for (int i = 0; i < 4; i++) {
            int r = arow + i * 16; if (r > NN - 1) r = NN - 1;
            af[i] = *(const bf16x8*)(As + (size_t)r * 288 + kk * 32 + koff);
        }
#pragma unroll
        for (int j = 0; j < 4; j++) {
            int ct = wc * 4 + j;
            bfr[j] = *(const bf16x8*)(Bs + (((size_t)kk * 8 + ct) * 64 + lane) * 8);
        }
#pragma unroll
        for (int i = 0; i < 4; i++)
#pragma unroll
            for (int j = 0; j < 4; j++)
                acc[i][j] = __builtin_amdgcn_mfma_f32_16x16x32_bf16(af[i], bfr[j], acc[i][j], 0, 0, 0);
    }

    const int c_base = wc * 64 + (lane & 15);
    const int r_quad = (lane >> 4) * 4;
#pragma unroll
    for (int j = 0; j < 4; j++) {
        int c = c_base + j * 16;
        if (c >= COUT) continue;
        float bias = b3[c] + lb3[c];
#pragma unroll
        for (int i = 0; i < 4; i++) {
            int nb = n0 + wr * 64 + i * 16 + r_quad;
#pragma unroll
            for (int q = 0; q < 4; q++) {
                int n = nb + q;
                if (n < NN) out[(size_t)n * COUT + c] = acc[i][j][q] + bias;
            }
        }
    }
}

extern "C" void kernel_launch(void* const* d_in, const int* in_sizes, int n_in,
                              void* d_out, int out_size, void* d_ws, size_t ws_size,
                              hipStream_t stream) {
    const float* x   = (const float*)d_in[0];
    const int*   ei  = (const int*)d_in[1];
    const float* W1  = (const float*)d_in[2];
    const float* as1 = (const float*)d_in[3];
    const float* ad1 = (const float*)d_in[4];
    const float* b1  = (const float*)d_in[5];
    const float* lw1 = (const float*)d_in[6];
    const float* lb1 = (const float*)d_in[7];
    const float* W2  = (const float*)d_in[8];
    const float* as2 = (const float*)d_in[9];
    const float* ad2 = (const float*)d_in[10];
    const float* b2  = (const float*)d_in[11];
    const float* lw2 = (const float*)d_in[12];
    const float* lb2 = (const float*)d_in[13];
    const float* W3  = (const float*)d_in[14];
    const float* as3 = (const float*)d_in[15];
    const float* ad3 = (const float*)d_in[16];
    const float* b3  = (const float*)d_in[17];
    const float* lw3 = (const float*)d_in[18];
    const float* lb3 = (const float*)d_in[19];
    float* out = (float*)d_out;
    float* ws  = (float*)d_ws;

    const int* esrc = ei;
    const int* edst = ei + NE;

    // ---- workspace layout (floats unless noted) ----
    // [0, 1.6M)      xbA (bf16) | hpA (bf16, layer 3) - same slot
    // [1.6M, 2.4M)   xcB (bf16, 100000x16) | hcB      - same slot
    // [4M, 8M)       agg
    // [8.8M, 9.6M)   adst ; [9.6M,...) Bc, Bf
    // [9.628M, 24.028M) zb (bf16)
    // [24.028M, ...) CSR ints
    __hip_bfloat16* xbA = (__hip_bfloat16*)ws;
    __hip_bfloat16* xcB = (__hip_bfloat16*)(ws + 1600000);
    float* agg  = ws + 4000000;
    float* adst = ws + 8800000;
    float* Bc   = ws + 9600000;
    __hip_bfloat16* Bf = (__hip_bfloat16*)(ws + 9608000);
    __hip_bfloat16* zb = (__hip_bfloat16*)(ws + 9628000);
    __hip_bfloat16* hpA = xbA;   // layer 3 reuses the same slots
    __hip_bfloat16* hcB = xcB;
    int* ib     = (int*)(ws + 24028000);
    int* deg    = ib;                 // 100,352
    int* off    = ib + 100352;        // 100,001 (+pad)
    int* bcnt   = ib + 200704;        // 128
    int* boff   = ib + 200832;        // 129
    int* bcur   = ib + 200992;        // 128
    int* bsum   = ib + 300704;        // 512
    int* bscan  = ib + 301216;        // 512
    int* sorted = ib + 301728;        // 1,700,000 -> ends 2,001,728
    int* ebuf   = ib + 2001728;       // 1,600,000 -> ends 3,601,728

    const int nodeBlocks = (NN + 255) / 256;       // 391
    const int binBlocks  = (NE + EPB - 1) / EPB;   // 196
    const int waveBlocks = NN / 4;                 // 25000
    const int featBlocks = (NN + 63) / 64;         // 1563 (64 rows/block)

    // ---- bucketed CSR build ----
    zero_bcnt_kernel<<<1, 256, 0, stream>>>(bcnt);
    bin_count_kernel<<<binBlocks, 256, 0, stream>>>(edst, bcnt);
    bin_scan_kernel<<<1, 256, 0, stream>>>(bcnt, boff, bcur);
    bin_place_kernel<<<binBlocks, 256, 0, stream>>>(esrc, edst, bcur, ebuf);
    bucket_deg_kernel<<<NB, 256, 0, stream>>>(boff, ebuf, deg);
    scan_block_kernel<<<nodeBlocks, 256, 0, stream>>>(deg, off, bsum);
    scan_bsum_kernel<<<1, 256, 0, stream>>>(bsum, bscan, nodeBlocks);
    place_kernel<<<nodeBlocks, 256, 0, stream>>>(off, bscan, sorted);
    bucket_scatter_kernel<<<NB, 256, 0, stream>>>(boff, ebuf, off, sorted);
    seg_sort_kernel<<<waveBlocks, 256, 0, stream>>>(off, sorted);

    // ---- layer 1 ----
    fold_B12_kernel<<<(FIN * 88 + 255) / 256, 256, 0, stream>>>(W1, lw1, as1, ad1, Bc, FIN);
    feature12_kernel<FIN><<<featBlocks, 256, 0, stream>>>(x, Bc, b1, lb1, xbA, xcB, agg, adst);
    agg4_csr_kernel<<<waveBlocks, 256, 0, stream>>>(off, sorted, adst, xbA, xcB, agg);

    // ---- layer 2 ----
    fold_B12_kernel<<<(HID * 88 + 255) / 256, 256, 0, stream>>>(W2, lw2, as2, ad2, Bc, HID);
    feature12_kernel<HID><<<featBlocks, 256, 0, stream>>>(agg, Bc, b2, lb2, xbA, xcB, agg, adst);
    agg4_csr_kernel<<<waveBlocks, 256, 0, stream>>>(off, sorted, adst, xbA, xcB, agg);

    // ---- layer 3 ----
    fold_B3_kernel<<<(40 * 12 + 255) / 256, 256, 0, stream>>>(W3, as3, ad3, Bc);
    fold_Bf_kernel<<<(9 * 8 * 64 * 8 + 255) / 256, 256, 0, stream>>>(W3, lw3, Bf);
    feature3_kernel<<<nodeBlocks, 256, 0, stream>>>(agg, Bc, adst, zb, hpA, hcB);
    z6_csr_kernel<<<waveBlocks, 256, 0, stream>>>(off, sorted, adst, hpA, hcB, zb);
    zgemm_mfma_kernel<<<(NN + 127) / 128, 256, 0, stream>>>(zb, Bf, b3, lb3, out);
}

// Round 14
// 498.120 us; speedup vs baseline: 1.0860x; 1.0860x over previous
//
#include <hip/hip_runtime.h>
#include <hip/hip_bf16.h>
#include <math.h>

// GAT x3 on N=100000 nodes, E=1600000 edges (+ self loops).
// Round 19: revert r18's seg_sort (clean null: FETCH/dur unchanged, cost
// +30us -> banding theory wrong; with mean degree 17 a wave consumes its
// segment in ~1 chunk, so intra-segment order doesn't change the cohort's
// line set). agg4 phase B -> 8-edge rounds (8 gathers in flight): the r17
// z6 result proved these kernels are gather-latency-bound and MLP depth
// pays when VGPR stays bounded; agg4's 8x is only ~+8 VGPR (1 head, scalar
// acc), unlike z6's 6-head 8x that sank r13. FMA order per edge unchanged.
// (R17: z6 4-edge MLP; R16: scores in featB line, 2 lines/edge; R15: bf16
// gather tables; R14: split aligned tables; R10: fused weights in LDS;
// R9: feature12 LDS-B; R8: bucketed CSR build.)

#define NN 100000
#define NE 1600000
#define NT (NE + NN)
#define FIN 50
#define HID 40
#define COUT 121

#define NB 128           // buckets
#define NPB 782          // nodes per bucket (128*782 = 100096 >= NN)
#define EPB 8192         // edges per bin block

typedef __attribute__((ext_vector_type(8))) short bf16x8;
typedef __attribute__((ext_vector_type(4))) float f32x4;

__device__ __forceinline__ float lrelu(float x) { return fmaxf(x, 0.2f * x); }
__device__ __forceinline__ float elu1(float x)  { return x > 0.f ? x : __expf(x) - 1.f; }
__device__ __forceinline__ unsigned pkbf(float a, float b) {
    __hip_bfloat16 ha = __float2bfloat16(a), hb = __float2bfloat16(b);
    return ((unsigned)*reinterpret_cast<unsigned short*>(&hb) << 16) |
           *reinterpret_cast<unsigned short*>(&ha);
}
__device__ __forceinline__ float bflo(unsigned u) { return __uint_as_float(u << 16); }
__device__ __forceinline__ float bfhi(unsigned u) { return __uint_as_float(u & 0xffff0000u); }

// ---------------- bucketed CSR build ----------------
__global__ __launch_bounds__(256)
void zero_bcnt_kernel(int* __restrict__ bcnt) {
    int t = threadIdx.x;
    if (t < NB) bcnt[t] = 0;
}

__global__ __launch_bounds__(256)
void bin_count_kernel(const int* __restrict__ edst, int* __restrict__ bcnt) {
    __shared__ int h[NB];
    int t = threadIdx.x;
    if (t < NB) h[t] = 0;
    __syncthreads();
    int e0 = blockIdx.x * EPB;
    for (int q = 0; q < EPB; q += 256) {
        int e = e0 + q + t;
        if (e < NE) atomicAdd(&h[edst[e] / NPB], 1);
    }
    __syncthreads();
    if (t < NB && h[t]) atomicAdd(&bcnt[t], h[t]);
}

__global__ __launch_bounds__(256)
void bin_scan_kernel(const int* __restrict__ bcnt, int* __restrict__ boff,
                     int* __restrict__ bcur) {
    __shared__ int s[NB];
    int t = threadIdx.x;
    if (t < NB) s[t] = bcnt[t];
    __syncthreads();
    if (t == 0) {
        int run = 0;
        for (int i = 0; i < NB; i++) { int c = s[i]; s[i] = run; run += c; }
        boff[NB] = run;   // == NE
    }
    __syncthreads();
    if (t < NB) { boff[t] = s[t]; bcur[t] = s[t]; }
}

// Each block claims a contiguous chunk per bucket, then writes packed records
// src | (dst_in_bucket << 17) into its exclusive chunk (dense, short window).
__global__ __launch_bounds__(256)
void bin_place_kernel(const int* __restrict__ esrc, const int* __restrict__ edst,
                      int* __restrict__ bcur, int* __restrict__ ebuf) {
    __shared__ int h[NB], base[NB], lcur[NB];
    int t = threadIdx.x;
    if (t < NB) h[t] = 0;
    __syncthreads();
    int e0 = blockIdx.x * EPB;
    for (int q = 0; q < EPB; q += 256) {
        int e = e0 + q + t;
        if (e < NE) atomicAdd(&h[edst[e] / NPB], 1);
    }
    __syncthreads();
    if (t < NB) {
        int c = h[t];
        base[t] = c ? atomicAdd(&bcur[t], c) : 0;
        lcur[t] = 0;
    }
    __syncthreads();
    for (int q = 0; q < EPB; q += 256) {
        int e = e0 + q + t;
        if (e < NE) {
            int d = edst[e], s = esrc[e];
            int b = d / NPB;
            int r = atomicAdd(&lcur[b], 1);
            ebuf[base[b] + r] = s | ((d - b * NPB) << 17);
        }
    }
}

// One block per bucket: per-node degree via LDS histogram.
__global__ __launch_bounds__(256)
void bucket_deg_kernel(const int* __restrict__ boff, const int* __restrict__ ebuf,
                       int* __restrict__ deg) {
    __shared__ int h[NPB];
    int b = blockIdx.x, t = threadIdx.x;
    for (int i = t; i < NPB; i += 256) h[i] = 0;
    __syncthreads();
    int jb = boff[b], je = boff[b + 1];
    for (int j = jb + t; j < je; j += 256) atomicAdd(&h[ebuf[j] >> 17], 1);
    __syncthreads();
    int n0 = b * NPB;
    for (int i = t; i < NPB; i += 256) {
        int n = n0 + i;
        if (n < NN) deg[n] = h[i] + 1;   // +1 self loop
    }
}

// One block per bucket: replay records with LDS cursors; sorted_src writes
// land in this block's exclusive CSR range (L2-local, written back once).
__global__ __launch_bounds__(256)
void bucket_scatter_kernel(const int* __restrict__ boff, const int* __restrict__ ebuf,
                           const int* __restrict__ off, int* __restrict__ sorted_src) {
    __shared__ int lcur[NPB];
    int b = blockIdx.x, t = threadIdx.x;
    int n0 = b * NPB;
    for (int i = t; i < NPB; i += 256) {
        int n = n0 + i;
        lcur[i] = (n < NN) ? off[n] + 1 : 0;   // +1: self loop occupies slot 0
    }
    __syncthreads();
    int jb = boff[b], je = boff[b + 1];
    for (int j = jb + t; j < je; j += 256) {
        int rec = ebuf[j];
        int p = atomicAdd(&lcur[rec >> 17], 1);
        sorted_src[p] = rec & 0x1FFFF;
    }
}

// ---------------- node-offset scan ----------------
__global__ __launch_bounds__(256)
void scan_block_kernel(const int* __restrict__ deg, int* __restrict__ off,
                       int* __restrict__ bsum) {
    __shared__ int s[256];
    int t = threadIdx.x, b = blockIdx.x, i = b * 256 + t;
    int v = (i < NN) ? deg[i] : 0;
    s[t] = v; __syncthreads();
#pragma unroll
    for (int o = 1; o < 256; o <<= 1) {
        int x = (t >= o) ? s[t - o] : 0;
        __syncthreads();
        s[t] += x;
        __syncthreads();
    }
    if (i < NN) off[i] = s[t] - v;
    if (t == 255) bsum[b] = s[255];
}

__global__ __launch_bounds__(256)
void scan_bsum_kernel(const int* __restrict__ bsum, int* __restrict__ bscan, int nb) {
    __shared__ int s[256];
    int t = threadIdx.x;
    int carry = 0;
    int nc = (nb + 255) / 256;
    for (int c = 0; c < nc; c++) {
        int i = c * 256 + t;
        int v = (i < nb) ? bsum[i] : 0;
        s[t] = v; __syncthreads();
#pragma unroll
        for (int o = 1; o < 256; o <<= 1) {
            int x = (t >= o) ? s[t - o] : 0;
            __syncthreads();
            s[t] += x;
            __syncthreads();
        }
        if (i < nb) bscan[i] = carry + s[t] - v;
        carry += s[255];
        __syncthreads();
    }
}

__global__ __launch_bounds__(256)
void place_kernel(int* __restrict__ off, const int* __restrict__ bscan,
                  int* __restrict__ sorted_src) {
    int i = blockIdx.x * 256 + threadIdx.x;
    if (i == 0) off[NN] = NT;
    if (i < NN) {
        int o = off[i] + bscan[i >> 8];
        off[i] = o;
        sorted_src[o] = i;   // self loop first
    }
}

// ---------------- fold weight blocks ----------------
__global__ __launch_bounds__(256)
void fold_B12_kernel(const float* __restrict__ W, const float* __restrict__ lw,
                     const float* __restrict__ as_, const float* __restrict__ ad_,
                     float* __restrict__ B, int F) {
    int t = blockIdx.x * 256 + threadIdx.x;
    if (t >= F * 88) return;
    int f = t / 88, j = t - f * 88;
    float v = 0.f;
    if (j < 40) v = W[f * 40 + j];
    else if (j < 80) v = lw[f * 40 + (j - 40)];
    else if (j < 84) {
        int h = j - 80; float s = 0.f;
        for (int d = 0; d < 10; d++) s += W[f * 40 + h * 10 + d] * as_[h * 10 + d];
        v = s;
    } else {
        int h = j - 84; float s = 0.f;
        for (int d = 0; d < 10; d++) s += W[f * 40 + h * 10 + d] * ad_[h * 10 + d];
        v = s;
    }
    B[t] = v;
}

__global__ __launch_bounds__(256)
void fold_B3_kernel(const float* __restrict__ W3, const float* __restrict__ as3,
                    const float* __restrict__ ad3, float* __restrict__ B) {
    int t = blockIdx.x * 256 + threadIdx.x;
    if (t >= 40 * 12) return;
    int f = t / 12, k = t - f * 12;
    float s = 0.f;
    if (k < 6) {
        int h = k;
        for (int c = 0; c < COUT; c++) s += W3[f * 726 + h * COUT + c] * as3[h * COUT + c];
    } else {
        int h = k - 6;
        for (int c = 0; c < COUT; c++) s += W3[f * 726 + h * COUT + c] * ad3[h * COUT + c];
    }
    B[t] = s;
}

// Fold W3/lw3 into bf16 MFMA B-fragment order.
__global__ __launch_bounds__(256)
void fold_Bf_kernel(const float* __restrict__ W3, const float* __restrict__ lw3,
                    __hip_bfloat16* __restrict__ Bf) {
    int t = blockIdx.x * 256 + threadIdx.x;
    if (t >= 9 * 8 * 64 * 8) return;
    int j = t & 7, lane = (t >> 3) & 63, ct = (t >> 9) & 7, kt = t >> 12;
    int k = kt * 32 + (lane >> 4) * 8 + j;
    int c = ct * 16 + (lane & 15);
    float v = 0.f;
    if (c < COUT) {
        if (k < 240) {
            int h = k / 40, f = k - h * 40;
            v = W3[f * 726 + h * COUT + c];
        } else if (k < 280) {
            int f = k - 240;
            v = lw3[f * COUT + c];
        }
    }
    Bf[t] = __float2bfloat16(v);
}

// ---------------- fused feature GEMM for layers 1/2 ----------------
// Gather tables: f<32 -> xbA (64B aligned bf16 rows); f in [32,40) + asrc
// scores -> combined xcB[node][16] bf16 (32B rows): [0:8]=feats, [8:12]=
// scores bf16. adst/agg stay fp32.
template <int F>
__global__ __launch_bounds__(256)
void feature12_kernel(const float* __restrict__ A, const float* __restrict__ B,
                      const float* __restrict__ bias, const float* __restrict__ lbias,
                      __hip_bfloat16* __restrict__ xbA, __hip_bfloat16* __restrict__ xcB,
                      float* __restrict__ agg, float* __restrict__ adst) {
    __shared__ float sB[F * 88];
    const int t = threadIdx.x;
    for (int i = t; i < F * 88; i += 256) sB[i] = B[i];

    const int lane = t & 63;
    const int p = __builtin_amdgcn_readfirstlane(t >> 6);
    const int r = blockIdx.x * 64 + lane;
    const bool valid = r < NN;
    const int rr = valid ? r : NN - 1;

    float a[F];
    if (F % 4 == 0) {
        const float4* A4 = reinterpret_cast<const float4*>(A + (size_t)rr * F);
#pragma unroll
        for (int q = 0; q < F / 4; q++) {
            float4 v = A4[q];
            a[4 * q] = v.x; a[4 * q + 1] = v.y; a[4 * q + 2] = v.z; a[4 * q + 3] = v.w;
        }
    } else {
        const float2* A2 = reinterpret_cast<const float2*>(A + (size_t)rr * F);
#pragma unroll
        for (int q = 0; q < F / 2; q++) {
            float2 v = A2[q];
            a[2 * q] = v.x; a[2 * q + 1] = v.y;
        }
        if (F & 1) a[F - 1] = A[(size_t)rr * F + F - 1];
    }
    __syncthreads();

    for (int g = p; g < 11; g += 4) {
        const int j0 = g * 8;
        float acc[8];
#pragma unroll
        for (int k = 0; k < 8; k++) acc[k] = 0.f;
#pragma unroll
        for (int f = 0; f < F; f++) {
            float av = a[f];
            float4 b0 = *reinterpret_cast<const float4*>(&sB[f * 88 + j0]);
            float4 b1 = *reinterpret_cast<const float4*>(&sB[f * 88 + j0 + 4]);
            acc[0] += av * b0.x; acc[1] += av * b0.y;
            acc[2] += av * b0.z; acc[3] += av * b0.w;
            acc[4] += av * b1.x; acc[5] += av * b1.y;
            acc[6] += av * b1.z; acc[7] += av * b1.w;
        }
        if (!valid) continue;
        if (j0 < 32) {
            uint4 v;
            v.x = pkbf(acc[0], acc[1]); v.y = pkbf(acc[2], acc[3]);
            v.z = pkbf(acc[4], acc[5]); v.w = pkbf(acc[6], acc[7]);
            *reinterpret_cast<uint4*>(&xbA[(size_t)r * 32 + j0]) = v;
        } else if (j0 < 40) {   // j0 == 32: tail features -> xcB[0:8]
            uint4 v;
            v.x = pkbf(acc[0], acc[1]); v.y = pkbf(acc[2], acc[3]);
            v.z = pkbf(acc[4], acc[5]); v.w = pkbf(acc[6], acc[7]);
            *reinterpret_cast<uint4*>(&xcB[(size_t)r * 16]) = v;
        } else if (j0 < 80) {
            int j = j0 - 40;
#pragma unroll
            for (int k = 0; k < 8; k++) acc[k] += bias[j + k] + lbias[j + k];
            *reinterpret_cast<float4*>(agg + (size_t)r * 40 + j) =
                make_float4(acc[0], acc[1], acc[2], acc[3]);
            *reinterpret_cast<float4*>(agg + (size_t)r * 40 + j + 4) =
                make_float4(acc[4], acc[5], acc[6], acc[7]);
        } else {                // j0 == 80: scores -> xcB[8:12] bf16; adst fp32
            uint2 sv;
            sv.x = pkbf(acc[0], acc[1]); sv.y = pkbf(acc[2], acc[3]);
            *reinterpret_cast<uint2*>(&xcB[(size_t)r * 16 + 8]) = sv;
            *reinterpret_cast<float4*>(adst + (size_t)r * 8) =
                make_float4(acc[4], acc[5], acc[6], acc[7]);
        }
    }
}

// ---------------- layer 3 scores + bf16 h2 copies (zb + hpA + combined hcB) -
__global__ __launch_bounds__(256)
void feature3_kernel(const float* __restrict__ A, const float* __restrict__ B,
                     float* __restrict__ adst, __hip_bfloat16* __restrict__ zb,
                     __hip_bfloat16* __restrict__ hpA, __hip_bfloat16* __restrict__ hcB) {
    int r = blockIdx.x * 256 + threadIdx.x;
    if (r >= NN) return;
    float a[40];
    const float4* A4 = reinterpret_cast<const float4*>(A + (size_t)r * 40);
#pragma unroll
    for (int q = 0; q < 10; q++) {
        float4 v = A4[q];
        a[4 * q] = v.x; a[4 * q + 1] = v.y; a[4 * q + 2] = v.z; a[4 * q + 3] = v.w;
    }
    __hip_bfloat16* zr = zb + (size_t)r * 288 + 240;
    __hip_bfloat16* ha = hpA + (size_t)r * 32;
    __hip_bfloat16* hb = hcB + (size_t)r * 16;
#pragma unroll
    for (int f = 0; f < 40; f++) {
        __hip_bfloat16 v = __float2bfloat16(a[f]);
        zr[f] = v;
        if (f < 32) ha[f] = v; else hb[f - 32] = v;
    }
#pragma unroll
    for (int f = 40; f < 48; f++) zr[f] = __float2bfloat16(0.f);

    float acc[12];
#pragma unroll
    for (int k = 0; k < 12; k++) acc[k] = 0.f;
#pragma unroll
    for (int f = 0; f < 40; f++) {
        float av = a[f];
#pragma unroll
        for (int k = 0; k < 12; k++) acc[k] += av * B[f * 12 + k];
    }
    uint4 sv;
    sv.x = pkbf(acc[0], acc[1]); sv.y = pkbf(acc[2], acc[3]);
    sv.z = pkbf(acc[4], acc[5]); sv.w = 0u;
    *reinterpret_cast<uint4*>(&hcB[(size_t)r * 16 + 8]) = sv;   // scores [8:14]
    *reinterpret_cast<float4*>(adst + (size_t)r * 8) = make_float4(acc[6], acc[7], acc[8], acc[9]);
    *reinterpret_cast<float2*>(adst + (size_t)r * 8 + 4) = make_float2(acc[10], acc[11]);
}

// ---------------- CSR aggregation, H=4, fused weights (LDS), fused ELU ------
// Round-10 structure, 2 lines/edge: xbA (64B row) + xcB (32B row: tail feats
// AND scores in the same line). Phase B: 8-edge rounds (8 gathers in flight).
__global__ __launch_bounds__(256)
void agg4_csr_kernel(const int* __restrict__ off, const int* __restrict__ srt,
                     const float* __restrict__ adst,
                     const __hip_bfloat16* __restrict__ xbA,
                     const __hip_bfloat16* __restrict__ xcB, float* agg) {
    __shared__ float sW[4][64 * 4];
    __shared__ int   sS[4][64];
    int t = threadIdx.x;
    int wslot = t >> 6;
    int wid = (blockIdx.x * 256 + t) >> 6;
    int d = __builtin_amdgcn_readfirstlane(wid);
    if (d >= NN) return;
    int lane = t & 63;
    bool act = lane < 40;
    int f = act ? lane : 0;
    int hh = f / 10;
    const __hip_bfloat16* xt = (f < 32) ? xbA : xcB;
    const int sh = (f < 32) ? 5 : 4;
    const int fo = (f < 32) ? f : (f - 32);
    float4 bv = *reinterpret_cast<const float4*>(adst + (size_t)d * 8);
    int jb = off[d], je = off[d + 1];
    float acc = 0.f, ds = 0.f;
    for (int c0 = jb; c0 < je; c0 += 64) {
        int cnt = je - c0; if (cnt > 64) cnt = 64;
        if (lane < cnt) {   // phase A: one lane per edge; bf16 scores
            int s = srt[c0 + lane];
            sS[wslot][lane] = s;
            uint2 sv = *reinterpret_cast<const uint2*>(&xcB[(size_t)s * 16 + 8]);
            float4 w;
            w.x = __expf(lrelu(bflo(sv.x) + bv.x));
            w.y = __expf(lrelu(bfhi(sv.x) + bv.y));
            w.z = __expf(lrelu(bflo(sv.y) + bv.z));
            w.w = __expf(lrelu(bfhi(sv.y) + bv.w));
            *reinterpret_cast<float4*>(&sW[wslot][lane * 4]) = w;
        }
        int j = 0;          // phase B: 8-edge rounds (8 gathers in flight)
        for (; j + 7 < cnt; j += 8) {
            int s0 = sS[wslot][j],     s1 = sS[wslot][j + 1];
            int s2 = sS[wslot][j + 2], s3 = sS[wslot][j + 3];
            int s4 = sS[wslot][j + 4], s5 = sS[wslot][j + 5];
            int s6 = sS[wslot][j + 6], s7 = sS[wslot][j + 7];
            float w0 = sW[wslot][(j + 0) * 4 + hh];
            float w1 = sW[wslot][(j + 1) * 4 + hh];
            float w2 = sW[wslot][(j + 2) * 4 + hh];
            float w3 = sW[wslot][(j + 3) * 4 + hh];
            float w4 = sW[wslot][(j + 4) * 4 + hh];
            float w5 = sW[wslot][(j + 5) * 4 + hh];
            float w6 = sW[wslot][(j + 6) * 4 + hh];
            float w7 = sW[wslot][(j + 7) * 4 + hh];
            float x0 = __bfloat162float(xt[((size_t)s0 << sh) + fo]);
            float x1 = __bfloat162float(xt[((size_t)s1 << sh) + fo]);
            float x2 = __bfloat162float(xt[((size_t)s2 << sh) + fo]);
            float x3 = __bfloat162float(xt[((size_t)s3 << sh) + fo]);
            float x4 = __bfloat162float(xt[((size_t)s4 << sh) + fo]);
            float x5 = __bfloat162float(xt[((size_t)s5 << sh) + fo]);
            float x6 = __bfloat162float(xt[((size_t)s6 << sh) + fo]);
            float x7 = __bfloat162float(xt[((size_t)s7 << sh) + fo]);
            acc += w0 * x0; acc += w1 * x1; acc += w2 * x2; acc += w3 * x3;
            ds += (w0 + w1) + (w2 + w3);
            acc += w4 * x4; acc += w5 * x5; acc += w6 * x6; acc += w7 * x7;
            ds += (w4 + w5) + (w6 + w7);
        }
        for (; j + 3 < cnt; j += 4) {
            int s0 = sS[wslot][j], s1 = sS[wslot][j + 1];
            int s2 = sS[wslot][j + 2], s3 = sS[wslot][j + 3];
            float w0 = sW[wslot][(j + 0) * 4 + hh];
            float w1 = sW[wslot][(j + 1) * 4 + hh];
            float w2 = sW[wslot][(j + 2) * 4 + hh];
            float w3 = sW[wslot][(j + 3) * 4 + hh];
            float x0 = __bfloat162float(xt[((size_t)s0 << sh) + fo]);
            float x1 = __bfloat162float(xt[((size_t)s1 << sh) + fo]);
            float x2 = __bfloat162float(xt[((size_t)s2 << sh) + fo]);
            float x3 = __bfloat162float(xt[((size_t)s3 << sh) + fo]);
            acc += w0 * x0; acc += w1 * x1; acc += w2 * x2; acc += w3 * x3;
            ds += (w0 + w1) + (w2 + w3);
        }
        for (; j < cnt; ++j) {
            int s = sS[wslot][j];
            float w = sW[wslot][j * 4 + hh];
            acc += w * __bfloat162float(xt[((size_t)s << sh) + fo]);
            ds += w;
        }
    }
    if (act) {
        float v = agg[(size_t)d * 40 + f] + acc / ds;
        agg[(size_t)d * 40 + f] = elu1(v);   // ELU fused (layers 1/2 only)
    }
}

// ---------------- CSR aggregation, H=6 -> bf16 z, fused weights (LDS) -------
// Round-10 structure, 2 lines/edge, 4-edge MLP rounds.
__global__ __launch_bounds__(256)
void z6_csr_kernel(const int* __restrict__ off, const int* __restrict__ srt,
                   const float* __restrict__ adst,
                   const __hip_bfloat16* __restrict__ hpA,
                   const __hip_bfloat16* __restrict__ hcB, __hip_bfloat16* zb) {
    __shared__ float sW[4][64 * 6];
    __shared__ int   sS[4][64];
    int t = threadIdx.x;
    int wslot = t >> 6;
    int wid = (blockIdx.x * 256 + t) >> 6;
    int d = __builtin_amdgcn_readfirstlane(wid);
    if (d >= NN) return;
    int lane = t & 63;
    bool act = lane < 40;
    int f = act ? lane : 0;
    const __hip_bfloat16* ht = (f < 32) ? hpA : hcB;
    const int sh = (f < 32) ? 5 : 4;
    const int fo = (f < 32) ? f : (f - 32);
    float4 bv0 = *reinterpret_cast<const float4*>(adst + (size_t)d * 8);
    float2 bv1 = *reinterpret_cast<const float2*>(adst + (size_t)d * 8 + 4);
    int jb = off[d], je = off[d + 1];
    float acc[6], ds[6];
#pragma unroll
    for (int h = 0; h < 6; h++) { acc[h] = 0.f; ds[h] = 0.f; }
    for (int c0 = jb; c0 < je; c0 += 64) {
        int cnt = je - c0; if (cnt > 64) cnt = 64;
        if (lane < cnt) {   // phase A: bf16 scores from the combined row
            int s = srt[c0 + lane];
            sS[wslot][lane] = s;
            uint4 sv = *reinterpret_cast<const uint4*>(&hcB[(size_t)s * 16 + 8]);
            float* wp = &sW[wslot][lane * 6];
            *reinterpret_cast<float4*>(wp) = make_float4(
                __expf(lrelu(bflo(sv.x) + bv0.x)), __expf(lrelu(bfhi(sv.x) + bv0.y)),
                __expf(lrelu(bflo(sv.y) + bv0.z)), __expf(lrelu(bfhi(sv.y) + bv0.w)));
            *reinterpret_cast<float2*>(wp + 4) = make_float2(
                __expf(lrelu(bflo(sv.z) + bv1.x)), __expf(lrelu(bfhi(sv.z) + bv1.y)));
        }
        int j = 0;          // phase B: 4-edge rounds (4 gathers in flight)
        for (; j + 3 < cnt; j += 4) {
            int s0 = sS[wslot][j],     s1 = sS[wslot][j + 1];
            int s2 = sS[wslot][j + 2], s3 = sS[wslot][j + 3];
            float hv0 = __bfloat162float(ht[((size_t)s0 << sh) + fo]);
            float hv1 = __bfloat162float(ht[((size_t)s1 << sh) + fo]);
            float hv2 = __bfloat162float(ht[((size_t)s2 << sh) + fo]);
            float hv3 = __bfloat162float(ht[((size_t)s3 << sh) + fo]);
            const float* wp = &sW[wslot][j * 6];
#pragma unroll
            for (int h = 0; h < 6; h++) {
                float w0 = wp[h], w1 = wp[6 + h], w2 = wp[12 + h], w3 = wp[18 + h];
                acc[h] += w0 * hv0; acc[h] += w1 * hv1;
                acc[h] += w2 * hv2; acc[h] += w3 * hv3;
                ds[h] += (w0 + w1) + (w2 + w3);
            }
        }
        for (; j + 1 < cnt; j += 2) {
            int s0 = sS[wslot][j], s1 = sS[wslot][j + 1];
            float hv0 = __bfloat162float(ht[((size_t)s0 << sh) + fo]);
            float hv1 = __bfloat162float(ht[((size_t)s1 << sh) + fo]);
            const float* wp = &sW[wslot][j * 6];
#pragma unroll
            for (int h = 0; h < 6; h++) {
                float w0 = wp[h], w1 = wp[6 + h];
                acc[h] += w0 * hv0; acc[h] += w1 * hv1;
                ds[h] += w0 + w1;
            }
        }
        for (; j < cnt; ++j) {
            int s = sS[wslot][j];
            float hv = __bfloat162float(ht[((size_t)s << sh) + fo]);
            const float* wp = &sW[wslot][j * 6];
#pragma unroll
            for (int h = 0; h < 6; h++) {
                acc[h] += wp[h] * hv;
                ds[h] += wp[h];
            }
        }
    }
    if (act) {
#pragma unroll
        for (int h = 0; h < 6; h++)
            zb[(size_t)d * 288 + h * 40 + f] =
                __float2bfloat16(acc[h] / ds[h] * (1.0f / 6.0f));
    }
}

// ---------------- MFMA GEMM: out[100000x121] = A[100000x288]@B[288x128] + bias
__global__ __launch_bounds__(256)
void zgemm_mfma_kernel(const __hip_bfloat16* __restrict__ Ab,
                       const __hip_bfloat16* __restrict__ Bf,
                       const float* __restrict__ b3, const float* __restrict__ lb3,
                       float* __restrict__ out) {
    const int t = threadIdx.x;
    const int lane = t & 63, w = t >> 6;
    const int wr = w & 1, wc = w >> 1;
    const int n0 = blockIdx.x * 128;
    const short* As = (const short*)Ab;
    const short* Bs = (const short*)Bf;

    f32x4 acc[4][4];
#pragma unroll
    for (int i = 0; i < 4; i++)
#pragma unroll
        for (int j = 0; j < 4; j++) acc[i][j] = (f32x4){0.f, 0.f, 0.f, 0.f};

    const int arow = n0 + wr * 64 + (lane & 15);
    const int koff = (lane >> 4) * 8;

    for (int kk = 0; kk < 9; kk++) {
        bf16x8 af[4], bfr[4];
#pragma unroll
        for (int i = 0; i < 4; i++) {
            int r = arow + i * 16; if (r > NN - 1) r = NN - 1;
            af[i] = *(const bf16x8*)(As + (size_t)r * 288 + kk * 32 + koff);
        }
#pragma unroll
        for (int j = 0; j < 4; j++) {
            int ct = wc * 4 + j;
            bfr[j] = *(const bf16x8*)(Bs + (((size_t)kk * 8 + ct) * 64 + lane) * 8);
        }
#pragma unroll
        for (int i = 0; i < 4; i++)
#pragma unroll
            for (int j = 0; j < 4; j++)
                acc[i][j] = __builtin_amdgcn_mfma_f32_16x16x32_bf16(af[i], bfr[j], acc[i][j], 0, 0, 0);
    }

    const int c_base = wc * 64 + (lane & 15);
    const int r_quad = (lane >> 4) * 4;
#pragma unroll
    for (int j = 0; j < 4; j++) {
        int c = c_base + j * 16;
        if (c >= COUT) continue;
        float bias = b3[c] + lb3[c];
#pragma unroll
        for (int i = 0; i < 4; i++) {
            int nb = n0 + wr * 64 + i * 16 + r_quad;
#pragma unroll
            for (int q = 0; q < 4; q++) {
                int n = nb + q;
                if (n < NN) out[(size_t)n * COUT + c] = acc[i][j][q] + bias;
            }
        }
    }
}

extern "C" void kernel_launch(void* const* d_in, const int* in_sizes, int n_in,
                              void* d_out, int out_size, void* d_ws, size_t ws_size,
                              hipStream_t stream) {
    const float* x   = (const float*)d_in[0];
    const int*   ei  = (const int*)d_in[1];
    const float* W1  = (const float*)d_in[2];
    const float* as1 = (const float*)d_in[3];
    const float* ad1 = (const float*)d_in[4];
    const float* b1  = (const float*)d_in[5];
    const float* lw1 = (const float*)d_in[6];
    const float* lb1 = (const float*)d_in[7];
    const float* W2  = (const float*)d_in[8];
    const float* as2 = (const float*)d_in[9];
    const float* ad2 = (const float*)d_in[10];
    const float* b2  = (const float*)d_in[11];
    const float* lw2 = (const float*)d_in[12];
    const float* lb2 = (const float*)d_in[13];
    const float* W3  = (const float*)d_in[14];
    const float* as3 = (const float*)d_in[15];
    const float* ad3 = (const float*)d_in[16];
    const float* b3  = (const float*)d_in[17];
    const float* lw3 = (const float*)d_in[18];
    const float* lb3 = (const float*)d_in[19];
    float* out = (float*)d_out;
    float* ws  = (float*)d_ws;

    const int* esrc = ei;
    const int* edst = ei + NE;

    // ---- workspace layout (floats unless noted) ----
    // [0, 1.6M)      xbA (bf16) | hpA (bf16, layer 3) - same slot
    // [1.6M, 2.4M)   xcB (bf16, 100000x16) | hcB      - same slot
    // [4M, 8M)       agg
    // [8.8M, 9.6M)   adst ; [9.6M,...) Bc, Bf
    // [9.628M, 24.028M) zb (bf16)
    // [24.028M, ...) CSR ints
    __hip_bfloat16* xbA = (__hip_bfloat16*)ws;
    __hip_bfloat16* xcB = (__hip_bfloat16*)(ws + 1600000);
    float* agg  = ws + 4000000;
    float* adst = ws + 8800000;
    float* Bc   = ws + 9600000;
    __hip_bfloat16* Bf = (__hip_bfloat16*)(ws + 9608000);
    __hip_bfloat16* zb = (__hip_bfloat16*)(ws + 9628000);
    __hip_bfloat16* hpA = xbA;   // layer 3 reuses the same slots
    __hip_bfloat16* hcB = xcB;
    int* ib     = (int*)(ws + 24028000);
    int* deg    = ib;                 // 100,352
    int* off    = ib + 100352;        // 100,001 (+pad)
    int* bcnt   = ib + 200704;        // 128
    int* boff   = ib + 200832;        // 129
    int* bcur   = ib + 200992;        // 128
    int* bsum   = ib + 300704;        // 512
    int* bscan  = ib + 301216;        // 512
    int* sorted = ib + 301728;        // 1,700,000 -> ends 2,001,728
    int* ebuf   = ib + 2001728;       // 1,600,000 -> ends 3,601,728

    const int nodeBlocks = (NN + 255) / 256;       // 391
    const int binBlocks  = (NE + EPB - 1) / EPB;   // 196
    const int waveBlocks = NN / 4;                 // 25000
    const int featBlocks = (NN + 63) / 64;         // 1563 (64 rows/block)

    // ---- bucketed CSR build ----
    zero_bcnt_kernel<<<1, 256, 0, stream>>>(bcnt);
    bin_count_kernel<<<binBlocks, 256, 0, stream>>>(edst, bcnt);
    bin_scan_kernel<<<1, 256, 0, stream>>>(bcnt, boff, bcur);
    bin_place_kernel<<<binBlocks, 256, 0, stream>>>(esrc, edst, bcur, ebuf);
    bucket_deg_kernel<<<NB, 256, 0, stream>>>(boff, ebuf, deg);
    scan_block_kernel<<<nodeBlocks, 256, 0, stream>>>(deg, off, bsum);
    scan_bsum_kernel<<<1, 256, 0, stream>>>(bsum, bscan, nodeBlocks);
    place_kernel<<<nodeBlocks, 256, 0, stream>>>(off, bscan, sorted);
    bucket_scatter_kernel<<<NB, 256, 0, stream>>>(boff, ebuf, off, sorted);

    // ---- layer 1 ----
    fold_B12_kernel<<<(FIN * 88 + 255) / 256, 256, 0, stream>>>(W1, lw1, as1, ad1, Bc, FIN);
    feature12_kernel<FIN><<<featBlocks, 256, 0, stream>>>(x, Bc, b1, lb1, xbA, xcB, agg, adst);
    agg4_csr_kernel<<<waveBlocks, 256, 0, stream>>>(off, sorted, adst, xbA, xcB, agg);

    // ---- layer 2 ----
    fold_B12_kernel<<<(HID * 88 + 255) / 256, 256, 0, stream>>>(W2, lw2, as2, ad2, Bc, HID);
    feature12_kernel<HID><<<featBlocks, 256, 0, stream>>>(agg, Bc, b2, lb2, xbA, xcB, agg, adst);
    agg4_csr_kernel<<<waveBlocks, 256, 0, stream>>>(off, sorted, adst, xbA, xcB, agg);

    // ---- layer 3 ----
    fold_B3_kernel<<<(40 * 12 + 255) / 256, 256, 0, stream>>>(W3, as3, ad3, Bc);
    fold_Bf_kernel<<<(9 * 8 * 64 * 8 + 255) / 256, 256, 0, stream>>>(W3, lw3, Bf);
    feature3_kernel<<<nodeBlocks, 256, 0, stream>>>(agg, Bc, adst, zb, hpA, hcB);
    z6_csr_kernel<<<waveBlocks, 256, 0, stream>>>(off, sorted, adst, hpA, hcB, zb);
    zgemm_mfma_kernel<<<(NN + 127) / 128, 256, 0, stream>>>(zb, Bf, b3, lb3, out);
}